// Round 1
// baseline (39.369 us; speedup 1.0000x reference)
//
#include <hip/hip_runtime.h>
#include <math.h>

#define EPS_CLIP 1e-6f
#define BPB 4          // b-values per 256-thread block (one wave per b)
#define MAXS 16        // Rsym LDS sized for up to 16 symmetry ops (S=12 here)

__global__ __launch_bounds__(256) void sym_loss_kernel(
    const float* __restrict__ R_pred,   // (B, 64, 3, 3)
    const float* __restrict__ R_gt,     // (B, 3, 3)
    const float* __restrict__ rot,      // (S, 3, 3)
    float* __restrict__ partial,        // (B/BPB,)
    int S)
{
    __shared__ float sP[BPB * 64 * 9];      // 2304 floats = 9216 B
    __shared__ float sR[BPB * MAXS * 9];    // Rsym per (b, s)
    __shared__ float sLoss[BPB];

    const int tid = threadIdx.x;
    const int b0  = blockIdx.x * BPB;

    // ---- stage R_pred tile (coalesced float4) ----
    const float4* src4 = reinterpret_cast<const float4*>(R_pred + (size_t)b0 * 64 * 9);
    float4* dst4 = reinterpret_cast<float4*>(sP);
    const int n4 = BPB * 64 * 9 / 4;        // 576
    for (int i = tid; i < n4; i += 256) dst4[i] = src4[i];

    // ---- cooperatively compute Rsym[bi][s] = rot[s] @ G[bi]  (BPB*S*9 tasks) ----
    const int ntask = BPB * S * 9;
    for (int t = tid; t < ntask; t += 256) {
        const int bi = t / (S * 9);
        const int r  = t % (S * 9);
        const int s  = r / 9;
        const int e  = r % 9;
        const int i  = e / 3, j = e % 3;
        const float* G  = R_gt + (size_t)(b0 + bi) * 9;
        const float* Rs = rot + s * 9;
        sR[(bi * S + s) * 9 + e] =
            fmaf(Rs[i*3+0], G[0*3+j],
            fmaf(Rs[i*3+1], G[1*3+j],
                 Rs[i*3+2] * G[2*3+j]));
    }
    __syncthreads();

    // ---- per-thread: trace dot against all S sym ops, keep max ----
    const int c  = tid & 63;   // candidate index (wave lane)
    const int bi = tid >> 6;   // which b within block (one wave per b)

    float p[9];
    const float* Pp = sP + (bi * 64 + c) * 9;
    #pragma unroll
    for (int e = 0; e < 9; ++e) p[e] = Pp[e];

    float m = -1e30f;
    for (int s = 0; s < S; ++s) {
        const float* Rs = sR + (bi * S + s) * 9;   // same addr across wave -> broadcast
        float tr = 0.f;
        #pragma unroll
        for (int e = 0; e < 9; ++e) tr = fmaf(p[e], Rs[e], tr);
        m = fmaxf(m, tr);
    }

    // ---- wave-reduce max over the 64 candidate lanes ----
    #pragma unroll
    for (int off = 32; off; off >>= 1) m = fmaxf(m, __shfl_xor(m, off));

    if (c == 0) {
        float cosv = (m - 1.0f) * 0.5f;
        cosv = fminf(fmaxf(cosv, -1.0f + EPS_CLIP), 1.0f - EPS_CLIP);
        sLoss[bi] = acosf(cosv);    // min over (c,s) of arccos == arccos of max trace
    }
    __syncthreads();

    if (tid == 0) {
        float sum = 0.f;
        #pragma unroll
        for (int i = 0; i < BPB; ++i) sum += sLoss[i];
        partial[blockIdx.x] = sum;
    }
}

__global__ __launch_bounds__(256) void reduce_kernel(
    const float* __restrict__ partial, int n, float* __restrict__ out, float invB)
{
    float sum = 0.f;
    for (int i = threadIdx.x; i < n; i += 256) sum += partial[i];
    #pragma unroll
    for (int off = 32; off; off >>= 1) sum += __shfl_xor(sum, off);
    __shared__ float ws[4];
    const int w = threadIdx.x >> 6;
    if ((threadIdx.x & 63) == 0) ws[w] = sum;
    __syncthreads();
    if (threadIdx.x == 0) out[0] = (ws[0] + ws[1] + ws[2] + ws[3]) * invB;
}

extern "C" void kernel_launch(void* const* d_in, const int* in_sizes, int n_in,
                              void* d_out, int out_size, void* d_ws, size_t ws_size,
                              hipStream_t stream) {
    const float* R_pred = (const float*)d_in[0];
    const float* R_gt   = (const float*)d_in[1];
    const float* rot    = (const float*)d_in[2];
    float* out = (float*)d_out;

    const int B = in_sizes[1] / 9;         // 32768
    const int S = in_sizes[2] / 9;         // 12
    const int nblocks = B / BPB;           // 8192

    float* partial = (float*)d_ws;         // nblocks * 4 bytes = 32 KiB

    sym_loss_kernel<<<nblocks, 256, 0, stream>>>(R_pred, R_gt, rot, partial, S);
    reduce_kernel<<<1, 256, 0, stream>>>(partial, nblocks, out, 1.0f / (float)B);
}

// Round 2
// 25.404 us; speedup vs baseline: 1.5497x; 1.5497x over previous
//
#include <hip/hip_runtime.h>
#include <math.h>

#define EPS_CLIP 1e-6f
#define BPB 4          // b-values per 256-thread block (one wave per b)

// SS = compile-time S (0 -> use runtime S_rt)
template <int SS>
__global__ __launch_bounds__(256) void sym_loss_kernel(
    const float* __restrict__ R_pred,   // (B, 64, 3, 3)
    const float* __restrict__ R_gt,     // (B, 3, 3)
    const float* __restrict__ rot,      // (S, 3, 3)
    float* __restrict__ partial,        // (B/BPB,)
    int S_rt)
{
    const int S = SS ? SS : S_rt;

    __shared__ float sP[BPB * 64 * 9];      // 9216 B
    __shared__ float sLoss[BPB];

    const int tid = threadIdx.x;
    const int b0  = blockIdx.x * BPB;

    // ---- stage R_pred tile (coalesced float4) ----
    const float4* src4 = reinterpret_cast<const float4*>(R_pred + (size_t)b0 * 64 * 9);
    float4* dst4 = reinterpret_cast<float4*>(sP);
    #pragma unroll
    for (int i = 0; i < 3; ++i) {
        const int idx = tid + i * 256;
        if (idx < BPB * 64 * 9 / 4) dst4[idx] = src4[idx];
    }
    __syncthreads();

    const int c  = tid & 63;   // candidate (wave lane)
    const int bi = tid >> 6;   // wave index = which b in block
    const int b  = b0 + bi;

    // ---- P from LDS (stride 9 dwords: odd -> ~2-way bank aliasing, free) ----
    float p[9];
    const float* Pp = sP + (bi * 64 + c) * 9;
    #pragma unroll
    for (int e = 0; e < 9; ++e) p[e] = Pp[e];

    // ---- G (wave-uniform address -> one L1 transaction per element) ----
    const float* G = R_gt + (size_t)b * 9;
    float g[9];
    #pragma unroll
    for (int e = 0; e < 9; ++e) g[e] = G[e];

    // ---- Q = P * G^T : Q[i][j] = sum_k P[i][k] * G[j][k]  (27 FMA) ----
    // trace(P @ (rot_s @ G)^T) = <P @ G^T, rot_s>  (cyclic trace identity)
    float q[9];
    #pragma unroll
    for (int i = 0; i < 3; ++i)
        #pragma unroll
        for (int j = 0; j < 3; ++j)
            q[i * 3 + j] = fmaf(p[i * 3 + 0], g[j * 3 + 0],
                           fmaf(p[i * 3 + 1], g[j * 3 + 1],
                                p[i * 3 + 2] * g[j * 3 + 2]));

    // ---- 12 dot products against rot (uniform address -> SGPR s_loads) ----
    float m = -1e30f;
    #pragma unroll
    for (int s = 0; s < (SS ? SS : 1) * (SS ? 1 : 1); ++s) { }  // (no-op; keep structure simple)
    if (SS) {
        #pragma unroll
        for (int s = 0; s < SS; ++s) {
            const float* Rs = rot + s * 9;
            float tr = 0.f;
            #pragma unroll
            for (int e = 0; e < 9; ++e) tr = fmaf(q[e], Rs[e], tr);
            m = fmaxf(m, tr);
        }
    } else {
        for (int s = 0; s < S; ++s) {
            const float* Rs = rot + s * 9;
            float tr = 0.f;
            #pragma unroll
            for (int e = 0; e < 9; ++e) tr = fmaf(q[e], Rs[e], tr);
            m = fmaxf(m, tr);
        }
    }

    // ---- wave-reduce max over 64 candidate lanes ----
    #pragma unroll
    for (int off = 32; off; off >>= 1) m = fmaxf(m, __shfl_xor(m, off));

    if (c == 0) {
        float cosv = (m - 1.0f) * 0.5f;
        cosv = fminf(fmaxf(cosv, -1.0f + EPS_CLIP), 1.0f - EPS_CLIP);
        sLoss[bi] = acosf(cosv);   // min over (c,s) of arccos == arccos of max trace
    }
    __syncthreads();

    if (tid == 0) {
        float sum = 0.f;
        #pragma unroll
        for (int i = 0; i < BPB; ++i) sum += sLoss[i];
        partial[blockIdx.x] = sum;
    }
}

__global__ __launch_bounds__(1024) void reduce_kernel(
    const float* __restrict__ partial, int n, float* __restrict__ out, float invB)
{
    float sum = 0.f;
    for (int i = threadIdx.x; i < n; i += 1024) sum += partial[i];
    #pragma unroll
    for (int off = 32; off; off >>= 1) sum += __shfl_xor(sum, off);
    __shared__ float ws[16];
    const int w = threadIdx.x >> 6;
    if ((threadIdx.x & 63) == 0) ws[w] = sum;
    __syncthreads();
    if (threadIdx.x == 0) {
        float t = 0.f;
        #pragma unroll
        for (int i = 0; i < 16; ++i) t += ws[i];
        out[0] = t * invB;
    }
}

extern "C" void kernel_launch(void* const* d_in, const int* in_sizes, int n_in,
                              void* d_out, int out_size, void* d_ws, size_t ws_size,
                              hipStream_t stream) {
    const float* R_pred = (const float*)d_in[0];
    const float* R_gt   = (const float*)d_in[1];
    const float* rot    = (const float*)d_in[2];
    float* out = (float*)d_out;

    const int B = in_sizes[1] / 9;         // 32768
    const int S = in_sizes[2] / 9;         // 12
    const int nblocks = B / BPB;           // 8192

    float* partial = (float*)d_ws;         // nblocks * 4 B = 32 KiB

    if (S == 12)
        sym_loss_kernel<12><<<nblocks, 256, 0, stream>>>(R_pred, R_gt, rot, partial, S);
    else
        sym_loss_kernel<0><<<nblocks, 256, 0, stream>>>(R_pred, R_gt, rot, partial, S);

    reduce_kernel<<<1, 1024, 0, stream>>>(partial, nblocks, out, 1.0f / (float)B);
}

// Round 3
// 24.505 us; speedup vs baseline: 1.6065x; 1.0367x over previous
//
#include <hip/hip_runtime.h>
#include <math.h>

#define EPS_CLIP 1e-6f
#define BPB 4                               // b-values per tile (one wave per b)
#define TILES 4                             // tiles per block (grid-stride depth)
#define NF4 (BPB * 64 * 9 / 4)              // 576 float4 per tile

// SS = compile-time S (0 -> runtime S_rt)
template <int SS>
__global__ __launch_bounds__(256) void sym_loss_kernel(
    const float* __restrict__ R_pred,   // (B, 64, 3, 3)
    const float* __restrict__ R_gt,     // (B, 3, 3)
    const float* __restrict__ rot,      // (S, 3, 3)
    float* __restrict__ partial,        // (gridDim.x,)
    int S_rt, int nTiles)
{
    const int S = SS ? SS : S_rt;

    __shared__ float sP[2][BPB * 64 * 9];   // 2 x 9216 B double buffer
    __shared__ float sLoss[BPB];

    const int tid = threadIdx.x;
    const int c   = tid & 63;               // candidate (wave lane)
    const int bi  = tid >> 6;               // wave index = b within tile
    const int t0  = blockIdx.x * TILES;

    const float4* src4 = reinterpret_cast<const float4*>(R_pred);

    // ---- prefetch tile t0 into registers (coalesced float4) ----
    float4 r0, r1, r2;
    {
        const size_t base = (size_t)t0 * NF4;
        r0 = src4[base + tid];
        r1 = src4[base + tid + 256];
        if (tid < NF4 - 512) r2 = src4[base + tid + 512];
    }

    float lsum = 0.f;
    int buf = 0;

    #pragma unroll
    for (int k = 0; k < TILES; ++k) {
        const int t = t0 + k;

        // ---- write staged registers to LDS[buf] ----
        float4* dst4 = reinterpret_cast<float4*>(sP[buf]);
        dst4[tid]       = r0;
        dst4[tid + 256] = r1;
        if (tid < NF4 - 512) dst4[tid + 512] = r2;
        __syncthreads();   // LDS[buf] ready; everyone done reading LDS[buf^1] two iters ago

        // ---- prefetch next tile while computing this one ----
        if (k + 1 < TILES && t + 1 < nTiles) {
            const size_t base = (size_t)(t + 1) * NF4;
            r0 = src4[base + tid];
            r1 = src4[base + tid + 256];
            if (tid < NF4 - 512) r2 = src4[base + tid + 512];
        }

        // ---- compute: one wave per b ----
        const int b = t * BPB + bi;

        float p[9];
        const float* Pp = sP[buf] + (bi * 64 + c) * 9;   // stride 9 dwords: odd -> free aliasing
        #pragma unroll
        for (int e = 0; e < 9; ++e) p[e] = Pp[e];

        // G: wave-uniform address forced to scalar loads
        const int bu = __builtin_amdgcn_readfirstlane(b);
        const float* G = R_gt + (size_t)bu * 9;
        float g[9];
        #pragma unroll
        for (int e = 0; e < 9; ++e) g[e] = G[e];

        // Q = P * G^T  (27 FMA);  trace(P @ (rot_s @ G)^T) = <Q, rot_s>
        float q[9];
        #pragma unroll
        for (int i = 0; i < 3; ++i)
            #pragma unroll
            for (int j = 0; j < 3; ++j)
                q[i * 3 + j] = fmaf(p[i * 3 + 0], g[j * 3 + 0],
                               fmaf(p[i * 3 + 1], g[j * 3 + 1],
                                    p[i * 3 + 2] * g[j * 3 + 2]));

        // 12 dots against rot (grid-uniform address -> scalar cache)
        float m = -1e30f;
        if (SS) {
            #pragma unroll
            for (int s = 0; s < SS; ++s) {
                const float* Rs = rot + s * 9;
                float tr = 0.f;
                #pragma unroll
                for (int e = 0; e < 9; ++e) tr = fmaf(q[e], Rs[e], tr);
                m = fmaxf(m, tr);
            }
        } else {
            for (int s = 0; s < S; ++s) {
                const float* Rs = rot + s * 9;
                float tr = 0.f;
                #pragma unroll
                for (int e = 0; e < 9; ++e) tr = fmaf(q[e], Rs[e], tr);
                m = fmaxf(m, tr);
            }
        }

        // wave-reduce max over 64 candidate lanes
        #pragma unroll
        for (int off = 32; off; off >>= 1) m = fmaxf(m, __shfl_xor(m, off));

        if (c == 0) {
            float cosv = (m - 1.0f) * 0.5f;
            cosv = fminf(fmaxf(cosv, -1.0f + EPS_CLIP), 1.0f - EPS_CLIP);
            lsum += acosf(cosv);   // min over (c,s) of arccos == arccos of max trace
        }

        buf ^= 1;
    }

    if (c == 0) sLoss[bi] = lsum;
    __syncthreads();

    if (tid == 0) {
        float sum = 0.f;
        #pragma unroll
        for (int i = 0; i < BPB; ++i) sum += sLoss[i];
        partial[blockIdx.x] = sum;
    }
}

__global__ __launch_bounds__(256) void reduce_kernel(
    const float* __restrict__ partial, int n, float* __restrict__ out, float invB)
{
    float sum = 0.f;
    for (int i = threadIdx.x; i < n; i += 256) sum += partial[i];
    #pragma unroll
    for (int off = 32; off; off >>= 1) sum += __shfl_xor(sum, off);
    __shared__ float ws[4];
    const int w = threadIdx.x >> 6;
    if ((threadIdx.x & 63) == 0) ws[w] = sum;
    __syncthreads();
    if (threadIdx.x == 0) out[0] = (ws[0] + ws[1] + ws[2] + ws[3]) * invB;
}

extern "C" void kernel_launch(void* const* d_in, const int* in_sizes, int n_in,
                              void* d_out, int out_size, void* d_ws, size_t ws_size,
                              hipStream_t stream) {
    const float* R_pred = (const float*)d_in[0];
    const float* R_gt   = (const float*)d_in[1];
    const float* rot    = (const float*)d_in[2];
    float* out = (float*)d_out;

    const int B = in_sizes[1] / 9;               // 32768
    const int S = in_sizes[2] / 9;               // 12
    const int nTiles  = B / BPB;                 // 8192
    const int nBlocks = (nTiles + TILES - 1) / TILES;  // 2048

    float* partial = (float*)d_ws;               // nBlocks * 4 B

    if (S == 12)
        sym_loss_kernel<12><<<nBlocks, 256, 0, stream>>>(R_pred, R_gt, rot, partial, S, nTiles);
    else
        sym_loss_kernel<0><<<nBlocks, 256, 0, stream>>>(R_pred, R_gt, rot, partial, S, nTiles);

    reduce_kernel<<<1, 256, 0, stream>>>(partial, nBlocks, out, 1.0f / (float)B);
}

// Round 4
// 21.366 us; speedup vs baseline: 1.8426x; 1.1469x over previous
//
#include <hip/hip_runtime.h>
#include <math.h>

#define EPS_CLIP 1e-6f
#define WPB 4      // b's per wave (consecutive)
#define NWAVES 4   // waves per block

struct F3 { float x, y, z; };   // 12 B, 4-B aligned -> dwordx3-able

// SS = compile-time S (0 -> runtime S_rt)
template <int SS>
__global__ __launch_bounds__(256) void sym_loss_kernel(
    const float* __restrict__ R_pred,   // (B, 64, 3, 3)
    const float* __restrict__ R_gt,     // (B, 3, 3)
    const float* __restrict__ rot,      // (S, 3, 3)
    float* __restrict__ partial,        // (gridDim.x,)
    int S_rt)
{
    const int S    = SS ? SS : S_rt;
    const int tid  = threadIdx.x;
    const int lane = tid & 63;
    const int wid  = tid >> 6;
    const int gw   = __builtin_amdgcn_readfirstlane(blockIdx.x * NWAVES + wid);
    const int b0   = gw * WPB;          // wave handles b0 .. b0+WPB-1 (contiguous 9 KB stream)

    // rotating prefetch registers
    F3 a0, a1, a2;
    {
        const F3* src = reinterpret_cast<const F3*>(R_pred + ((size_t)b0 * 64 + lane) * 9);
        a0 = src[0]; a1 = src[1]; a2 = src[2];
    }

    float lsum = 0.f;

    #pragma unroll
    for (int k = 0; k < WPB; ++k) {
        const int b = __builtin_amdgcn_readfirstlane(b0 + k);

        // current candidate matrix from prefetch regs
        float p[9] = { a0.x, a0.y, a0.z, a1.x, a1.y, a1.z, a2.x, a2.y, a2.z };

        // issue next b's loads (latency hides under the ~150 VALU ops below)
        if (k + 1 < WPB) {
            const F3* src = reinterpret_cast<const F3*>(R_pred + ((size_t)(b + 1) * 64 + lane) * 9);
            a0 = src[0]; a1 = src[1]; a2 = src[2];
        }

        // G: wave-uniform address -> scalar loads
        const float* G = R_gt + (size_t)b * 9;
        float g[9];
        #pragma unroll
        for (int e = 0; e < 9; ++e) g[e] = G[e];

        // Q = P * G^T (27 FMA);  trace(P @ (rot_s @ G)^T) = <Q, rot_s>  (cyclic trace)
        float q[9];
        #pragma unroll
        for (int i = 0; i < 3; ++i)
            #pragma unroll
            for (int j = 0; j < 3; ++j)
                q[i * 3 + j] = fmaf(p[i * 3 + 0], g[j * 3 + 0],
                               fmaf(p[i * 3 + 1], g[j * 3 + 1],
                                    p[i * 3 + 2] * g[j * 3 + 2]));

        // S trace-dots against rot (grid-uniform -> SGPRs)
        float m = -1e30f;
        if (SS) {
            #pragma unroll
            for (int s = 0; s < SS; ++s) {
                const float* Rs = rot + s * 9;
                float tr = 0.f;
                #pragma unroll
                for (int e = 0; e < 9; ++e) tr = fmaf(q[e], Rs[e], tr);
                m = fmaxf(m, tr);
            }
        } else {
            for (int s = 0; s < S; ++s) {
                const float* Rs = rot + s * 9;
                float tr = 0.f;
                #pragma unroll
                for (int e = 0; e < 9; ++e) tr = fmaf(q[e], Rs[e], tr);
                m = fmaxf(m, tr);
            }
        }

        // max over the 64 candidate lanes
        #pragma unroll
        for (int off = 32; off; off >>= 1) m = fmaxf(m, __shfl_xor(m, off));

        if (lane == 0) {
            float cosv = (m - 1.0f) * 0.5f;
            cosv = fminf(fmaxf(cosv, -1.0f + EPS_CLIP), 1.0f - EPS_CLIP);
            lsum += acosf(cosv);   // min over (c,s) of arccos == arccos of max trace
        }
    }

    // combine the 4 wave sums
    __shared__ float sLoss[NWAVES];
    if (lane == 0) sLoss[wid] = lsum;
    __syncthreads();
    if (tid == 0) {
        float sum = 0.f;
        #pragma unroll
        for (int i = 0; i < NWAVES; ++i) sum += sLoss[i];
        partial[blockIdx.x] = sum;
    }
}

__global__ __launch_bounds__(1024) void reduce_kernel(
    const float* __restrict__ partial, int n, float* __restrict__ out, float invB)
{
    float sum = 0.f;
    for (int i = threadIdx.x; i < n; i += 1024) sum += partial[i];
    #pragma unroll
    for (int off = 32; off; off >>= 1) sum += __shfl_xor(sum, off);
    __shared__ float ws[16];
    const int w = threadIdx.x >> 6;
    if ((threadIdx.x & 63) == 0) ws[w] = sum;
    __syncthreads();
    if (threadIdx.x == 0) {
        float t = 0.f;
        #pragma unroll
        for (int i = 0; i < 16; ++i) t += ws[i];
        out[0] = t * invB;
    }
}

extern "C" void kernel_launch(void* const* d_in, const int* in_sizes, int n_in,
                              void* d_out, int out_size, void* d_ws, size_t ws_size,
                              hipStream_t stream) {
    const float* R_pred = (const float*)d_in[0];
    const float* R_gt   = (const float*)d_in[1];
    const float* rot    = (const float*)d_in[2];
    float* out = (float*)d_out;

    const int B = in_sizes[1] / 9;                       // 32768
    const int S = in_sizes[2] / 9;                       // 12
    const int nBlocks = B / (WPB * NWAVES);              // 2048

    float* partial = (float*)d_ws;                       // nBlocks * 4 B

    if (S == 12)
        sym_loss_kernel<12><<<nBlocks, 256, 0, stream>>>(R_pred, R_gt, rot, partial, S);
    else
        sym_loss_kernel<0><<<nBlocks, 256, 0, stream>>>(R_pred, R_gt, rot, partial, S);

    reduce_kernel<<<1, 1024, 0, stream>>>(partial, nBlocks, out, 1.0f / (float)B);
}